// Round 1
// baseline (1617.818 us; speedup 1.0000x reference)
//
#include <hip/hip_runtime.h>
#include <cstdint>

// N=100000 nodes, E=1.6M edges, D=32, 5D=160, ATTR=33
constexpr int D      = 32;
constexpr int FD     = 160;
constexpr int ATTRD  = 33;
constexpr int WTILE  = 16;    // edges per wave (fully independent waves, no barriers)
constexpr int BLOCK  = 256;   // 4 waves/block, wave w -> tile blockIdx*4+w
constexpr int NKS    = 5;     // K-steps of 32 for the 160-K GEMMs
constexpr int ASTR   = 168;   // per-wave X2 row stride (shorts): 336 B, 16B-aligned b128 reads
constexpr int SWSTR  = 36;    // sW row stride (floats): bank=(4*l15+8q+j)%32 -> 8 lanes per
                              // 4-bank group on b128 reads = LDS BW floor, conflict-free
constexpr int WBYTES = 5376;  // per-wave shared bytes = max(16*36*4=2304 sW, 16*168*2=5376 sA)
                              // sW dead after features stage (epilogue W kept in VGPRs), so
                              // sA aliases it -> LDS/block 21504 -> 7 blocks/CU (was 5)

typedef __attribute__((ext_vector_type(8))) short short8;  // 8 bf16 (4 VGPRs) MFMA A/B frag
typedef __attribute__((ext_vector_type(4))) float f32x4;   // MFMA C/D frag

__device__ __forceinline__ float fast_tanh(float x) {
    float e = __expf(2.0f * x);
    return 1.0f - 2.0f * __builtin_amdgcn_rcpf(e + 1.0f);
}
// RNE bf16, no NaN handling (inputs finite by construction)
__device__ __forceinline__ unsigned short bf16rne(float x) {
    union { float f; unsigned u; } v; v.f = x;
    unsigned r = v.u + 0x7fffu + ((v.u >> 16) & 1u);
    return (unsigned short)(r >> 16);
}

// Pack Wd1 (160x160) and W1 rows 0..31 (32x32) into bf16 B-fragment lane order.
// B-chunk (nt,ks): lane L holds B[ks*32 + (L>>4)*8 + j][nt*16 + (L&15)], j<8.
// ws layout (shorts): [0, 25600) Wd1 frags; [25600, 26624) W1 frags (K=32).
// W1 row 32 is applied as a rank-1 VALU correction in the kernel.
__global__ void prep_weights(const float* __restrict__ Wd1,
                             const float* __restrict__ W1,
                             unsigned short* __restrict__ wsb) {
    int t = blockIdx.x * blockDim.x + threadIdx.x;
    if (t < FD * FD) {
        int k = t / FD, n = t - k * FD;
        int nt = n >> 4, l15 = n & 15;
        int ks = k >> 5, quad = (k >> 3) & 3, j = k & 7;
        int dst = ((nt * NKS + ks) * 64 + quad * 16 + l15) * 8 + j;
        wsb[dst] = bf16rne(Wd1[t]);
    } else if (t < FD * FD + 32 * D) {
        int t2 = t - FD * FD;            // t2 = k*32 + n, k in [0,32)
        int k = t2 >> 5, n = t2 & 31;
        int nt = n >> 4, l15 = n & 15;
        int quad = k >> 3, j = k & 7;
        int dst = FD * FD + (nt * 64 + quad * 16 + l15) * 8 + j;
        wsb[dst] = bf16rne(W1[k * D + n]);
    }
}

// (256,7): 7 blocks/CU (LDS 21504/block), VGPR cap 73 (~64 needed). No
// __syncthreads anywhere: each wave owns 16 edges end-to-end; LDS regions are
// per-wave, same-wave ds_write->ds_read ordering is guaranteed by lgkmcnt.
// sW and sA alias one per-wave buffer: sW (silu(fc1)) is only read by the
// features stage; the epilogue uses the fc1 MFMA output kept in registers
// (identical layout: e=quad*4+r, c=par*16+l15). sA is written after mm1
// (strictly after the last sW read), so the alias is time-disjoint.
__global__ __launch_bounds__(BLOCK, 7)
void prop_mfma(const float* __restrict__ xn,
               const float* __restrict__ xe_attr,
               const float* __restrict__ W1,
               const float* __restrict__ b1,
               const unsigned short* __restrict__ wsb,
               const int*   __restrict__ esrc,
               const int*   __restrict__ edst,
               float* __restrict__ out,
               int E)
{
    __shared__ __align__(16) unsigned char sMem[4 * WBYTES];   // 21504 B/block

    const int tid  = threadIdx.x;
    const int lane = tid & 63;
    const int w    = tid >> 6;
    const int l15  = lane & 15;
    const int quad = lane >> 4;
    unsigned char* wbase = sMem + w * WBYTES;
    float*          sW = reinterpret_cast<float*>(wbase);          // [16][SWSTR] f32
    unsigned short* sA = reinterpret_cast<unsigned short*>(wbase); // [16][ASTR] bf16

    const long tile = (long)blockIdx.x * 4 + w;
    const long e0   = tile * WTILE;
    if (e0 >= (long)E) return;                      // wave-uniform, no barriers to miss
    const int nv = min(WTILE, (int)((long)E - e0));

    const short8* Bp  = reinterpret_cast<const short8*>(wsb);
    const short8* W1p = reinterpret_cast<const short8*>(wsb + FD * FD);

    // ---------------- fc1: W = silu(attr @ W1 + b1), A-frag direct from global ----
    // Post-silu values kept in Wr0/Wr1 (epilogue layout) AND written to sW
    // (features layout, stride 36 = conflict-free).
    float Wr0[4], Wr1[4];
    {
        int rowA = (int)e0 + ((l15 < nv) ? l15 : 0);
        const float* ar = xe_attr + (size_t)rowA * ATTRD + quad * 8;
        union { short8 v; unsigned short u[8]; } AF0;
        #pragma unroll
        for (int j = 0; j < 8; ++j) AF0.u[j] = bf16rne(ar[j]);

        f32x4 c0 = (f32x4){0.f, 0.f, 0.f, 0.f};
        f32x4 c1 = (f32x4){0.f, 0.f, 0.f, 0.f};
        c0 = __builtin_amdgcn_mfma_f32_16x16x32_bf16(AF0.v, W1p[lane],      c0, 0, 0, 0);
        c1 = __builtin_amdgcn_mfma_f32_16x16x32_bf16(AF0.v, W1p[64 + lane], c1, 0, 0, 0);

        // rank-1 correction for attr col 32, + bias, + silu
        float b1a  = b1[l15],            b1b  = b1[16 + l15];
        float w32a = W1[32 * D + l15],   w32b = W1[32 * D + 16 + l15];
        #pragma unroll
        for (int r = 0; r < 4; ++r) {
            int e = quad * 4 + r;
            int rowC = (int)e0 + ((e < nv) ? e : 0);
            float a32 = xe_attr[(size_t)rowC * ATTRD + 32];
            float x0 = c0[r] + b1a + a32 * w32a;
            float x1 = c1[r] + b1b + a32 * w32b;
            float s0 = x0 * __builtin_amdgcn_rcpf(1.0f + __expf(-x0));
            float s1 = x1 * __builtin_amdgcn_rcpf(1.0f + __expf(-x1));
            Wr0[r] = s0;
            Wr1[r] = s1;
            sW[e * SWSTR + l15]      = s0;
            sW[e * SWSTR + 16 + l15] = s1;
        }
    }

    // ---------------- features: lane owns edge l15, cols quad*8..+8 ----------------
    // A-frags for mm1 chunk ks=q are exactly this lane's feature q values.
    union { short8 v; unsigned short u[8]; } AF[5];
    {
        int ei = (int)e0 + ((l15 < nv) ? l15 : 0);
        int se = esrc[ei], de = edst[ei];
        const float4* xsr = reinterpret_cast<const float4*>(xn + (size_t)se * D + quad * 8);
        const float4* xdr = reinterpret_cast<const float4*>(xn + (size_t)de * D + quad * 8);
        float4 xs0 = xsr[0], xs1 = xsr[1];
        float4 xd0 = xdr[0], xd1 = xdr[1];
        float4 wv0 = *reinterpret_cast<const float4*>(&sW[l15 * SWSTR + quad * 8]);
        float4 wv1 = *reinterpret_cast<const float4*>(&sW[l15 * SWSTR + quad * 8 + 4]);
        float xs[8] = {xs0.x, xs0.y, xs0.z, xs0.w, xs1.x, xs1.y, xs1.z, xs1.w};
        float xd[8] = {xd0.x, xd0.y, xd0.z, xd0.w, xd1.x, xd1.y, xd1.z, xd1.w};
        float wf[8] = {wv0.x, wv0.y, wv0.z, wv0.w, wv1.x, wv1.y, wv1.z, wv1.w};
        #pragma unroll
        for (int c = 0; c < 8; ++c) {
            float g = wf[c] * (xs[c] - xd[c]);
            float a = wf[c] * (xs[c] + xd[c]) * 0.5f;
            AF[0].u[c] = bf16rne(fast_tanh(g));
            AF[1].u[c] = bf16rne(fast_tanh(a));
            AF[2].u[c] = bf16rne(fast_tanh(g * a));
            AF[3].u[c] = bf16rne(fast_tanh(g * g));
            AF[4].u[c] = bf16rne(fast_tanh(a * a));
        }
    }

    // ---------------- matmul 1: C[nt] (16 edges x 160 cols per wave) ----------------
    f32x4 C[10];
    #pragma unroll
    for (int t = 0; t < 10; ++t) C[t] = (f32x4){0.f, 0.f, 0.f, 0.f};
    #pragma unroll
    for (int ks = 0; ks < NKS; ++ks)
        #pragma unroll
        for (int nt = 0; nt < 10; ++nt)
            C[nt] = __builtin_amdgcn_mfma_f32_16x16x32_bf16(
                AF[ks].v, Bp[(nt * NKS + ks) * 64 + lane], C[nt], 0, 0, 0);

    // ---------------- tv_norm: full row in 16-lane group, shfl-only ----------------
    float mean[4], scale[4];
    #pragma unroll
    for (int r = 0; r < 4; ++r) {
        float s = 0.f, q = 0.f;
        #pragma unroll
        for (int t = 0; t < 10; ++t) { float v = C[t][r]; s += v; q += v * v; }
        #pragma unroll
        for (int m = 1; m < 16; m <<= 1) { s += __shfl_xor(s, m); q += __shfl_xor(q, m); }
        mean[r] = s * (1.0f / FD);
        scale[r] = __builtin_amdgcn_rsqf(q - (float)FD * mean[r] * mean[r] + 1e-3f);
    }

    // ---------------- tanh(tv_norm) -> wave-local LDS (transpose for mm2 A) --------
    // Overwrites the sW region (sW fully consumed in the features stage).
    #pragma unroll
    for (int t = 0; t < 10; ++t)
        #pragma unroll
        for (int r = 0; r < 4; ++r) {
            float v = fast_tanh((C[t][r] - mean[r]) * scale[r]);
            sA[(quad * 4 + r) * ASTR + t * 16 + l15] = bf16rne(v);
        }

    // ---------------- matmul 2 (A from wave-local LDS, same-wave ordering) ---------
    #pragma unroll
    for (int t = 0; t < 10; ++t) C[t] = (f32x4){0.f, 0.f, 0.f, 0.f};
    #pragma unroll
    for (int ks = 0; ks < NKS; ++ks) {
        short8 af2 = *reinterpret_cast<const short8*>(&sA[l15 * ASTR + ks * 32 + quad * 8]);
        #pragma unroll
        for (int nt = 0; nt < 10; ++nt)
            C[nt] = __builtin_amdgcn_mfma_f32_16x16x32_bf16(
                af2, Bp[(nt * NKS + ks) * 64 + lane], C[nt], 0, 0, 0);
    }

    // ---------------- epilogue: msg = tile(W,5)*tanh; chunk-reduce; atomics --------
    // W comes from registers (fc1 output layout == epilogue layout), no LDS read.
    #pragma unroll
    for (int r = 0; r < 4; ++r) {
        int e = quad * 4 + r;
        if (e >= nv) continue;
        int sd = edst[e0 + e], ss = esrc[e0 + e];
        #pragma unroll
        for (int par = 0; par < 2; ++par) {
            int c = par * 16 + l15;
            float wv = (par == 0) ? Wr0[r] : Wr1[r];
            float m0 = fast_tanh(C[par][r]) * wv;
            float A4 = (fast_tanh(C[par + 2][r]) + fast_tanh(C[par + 4][r])
                      + fast_tanh(C[par + 6][r]) + fast_tanh(C[par + 8][r])) * wv;
            atomicAdd(out + (size_t)sd * D + c, m0 + 0.5f * A4);
            atomicAdd(out + (size_t)ss * D + c, 0.5f * A4 - m0);
        }
    }
}

extern "C" void kernel_launch(void* const* d_in, const int* in_sizes, int n_in,
                              void* d_out, int out_size, void* d_ws, size_t ws_size,
                              hipStream_t stream)
{
    const float* xn   = (const float*)d_in[0];
    const float* attr = (const float*)d_in[1];
    const float* W1   = (const float*)d_in[2];
    const float* b1   = (const float*)d_in[3];
    const float* Wd1  = (const float*)d_in[4];
    const int*   esrc = (const int*)d_in[5];
    const int*   edst = (const int*)d_in[6];
    float* out = (float*)d_out;
    unsigned short* wsb = (unsigned short*)d_ws;   // 26624 bf16 packed B-frags

    const int E = in_sizes[5];

    hipMemsetAsync(d_out, 0, (size_t)out_size * sizeof(float), stream);
    prep_weights<<<(FD * FD + 32 * D + 255) / 256, 256, 0, stream>>>(Wd1, W1, wsb);
    const long tiles = ((long)E + WTILE - 1) / WTILE;
    const int grid = (int)((tiles + 3) / 4);
    prop_mfma<<<grid, BLOCK, 0, stream>>>(xn, attr, W1, b1, wsb, esrc, edst, out, E);
}

// Round 2
// 918.157 us; speedup vs baseline: 1.7620x; 1.7620x over previous
//
#include <hip/hip_runtime.h>
#include <cstdint>

// N=100000 nodes, E=1.6M edges, D=32, 5D=160, ATTR=33
constexpr int D      = 32;
constexpr int FD     = 160;
constexpr int ATTRD  = 33;
constexpr int WTILE  = 16;    // edges per wave (fully independent waves, no barriers)
constexpr int BLOCK  = 256;   // 4 waves/block, wave w -> tile blockIdx*4+w
constexpr int NKS    = 5;     // K-steps of 32 for the 160-K GEMMs
constexpr int ASTR   = 168;   // per-wave X2 row stride (shorts): 336 B, 16B-aligned b128 reads
constexpr int SWSTR  = 36;    // sW row stride (floats): bank=(4*l15+8q+j)%32 -> 8 lanes per
                              // 4-bank group on b128 reads = LDS BW floor, conflict-free
constexpr int WBYTES = 5376;  // per-wave shared bytes = max(16*36*4=2304 sW, 16*168*2=5376 sA)
                              // sW dead after features stage (epilogue W kept in VGPRs), so
                              // sA aliases it -> LDS/block 21504

typedef __attribute__((ext_vector_type(8))) short short8;  // 8 bf16 (4 VGPRs) MFMA A/B frag
typedef __attribute__((ext_vector_type(4))) float f32x4;   // MFMA C/D frag

__device__ __forceinline__ float fast_tanh(float x) {
    float e = __expf(2.0f * x);
    return 1.0f - 2.0f * __builtin_amdgcn_rcpf(e + 1.0f);
}
// RNE bf16, no NaN handling (inputs finite by construction)
__device__ __forceinline__ unsigned short bf16rne(float x) {
    union { float f; unsigned u; } v; v.f = x;
    unsigned r = v.u + 0x7fffu + ((v.u >> 16) & 1u);
    return (unsigned short)(r >> 16);
}

// Pack Wd1 (160x160) and W1 rows 0..31 (32x32) into bf16 B-fragment lane order.
// B-chunk (nt,ks): lane L holds B[ks*32 + (L>>4)*8 + j][nt*16 + (L&15)], j<8.
// ws layout (shorts): [0, 25600) Wd1 frags; [25600, 26624) W1 frags (K=32).
// W1 row 32 is applied as a rank-1 VALU correction in the kernel.
__global__ void prep_weights(const float* __restrict__ Wd1,
                             const float* __restrict__ W1,
                             unsigned short* __restrict__ wsb) {
    int t = blockIdx.x * blockDim.x + threadIdx.x;
    if (t < FD * FD) {
        int k = t / FD, n = t - k * FD;
        int nt = n >> 4, l15 = n & 15;
        int ks = k >> 5, quad = (k >> 3) & 3, j = k & 7;
        int dst = ((nt * NKS + ks) * 64 + quad * 16 + l15) * 8 + j;
        wsb[dst] = bf16rne(Wd1[t]);
    } else if (t < FD * FD + 32 * D) {
        int t2 = t - FD * FD;            // t2 = k*32 + n, k in [0,32)
        int k = t2 >> 5, n = t2 & 31;
        int nt = n >> 4, l15 = n & 15;
        int quad = k >> 3, j = k & 7;
        int dst = FD * FD + (nt * 64 + quad * 16 + l15) * 8 + j;
        wsb[dst] = bf16rne(W1[k * D + n]);
    }
}

// (256,5): VGPR cap 102 total (unified VGPR+AGPR file). Round-1 lesson: (256,7)
// cap 72 forced ~48 regs of spill (FETCH 272MB->1.7GB) -- the true live set is
// ~120 with AF[5] in registers. This version removes AF[5] entirely: features
// are written straight to sA in mm2's A-layout and mm1 reads its A-frag per
// K-step from LDS (1 ds_read_b128 per 10 MFMAs). Peak live ~90 regs.
// No __syncthreads anywhere: each wave owns 16 edges end-to-end; LDS regions
// are per-wave; same-wave ds ordering is program-order (DS ops in-order).
// Alias timeline within a wave: fc1 writes sW -> features reads sW (reads
// issue before any feature write in program order) -> features write sA
// (clobbers sW region) -> mm1 reads sA -> tvnorm/tanh overwrites sA -> mm2
// reads sA -> epilogue uses registers only.
__global__ __launch_bounds__(BLOCK, 5)
void prop_mfma(const float* __restrict__ xn,
               const float* __restrict__ xe_attr,
               const float* __restrict__ W1,
               const float* __restrict__ b1,
               const unsigned short* __restrict__ wsb,
               const int*   __restrict__ esrc,
               const int*   __restrict__ edst,
               float* __restrict__ out,
               int E)
{
    __shared__ __align__(16) unsigned char sMem[4 * WBYTES];   // 21504 B/block

    const int tid  = threadIdx.x;
    const int lane = tid & 63;
    const int w    = tid >> 6;
    const int l15  = lane & 15;
    const int quad = lane >> 4;
    unsigned char* wbase = sMem + w * WBYTES;
    float*          sW = reinterpret_cast<float*>(wbase);          // [16][SWSTR] f32
    unsigned short* sA = reinterpret_cast<unsigned short*>(wbase); // [16][ASTR] bf16

    const long tile = (long)blockIdx.x * 4 + w;
    const long e0   = tile * WTILE;
    if (e0 >= (long)E) return;                      // wave-uniform, no barriers to miss
    const int nv = min(WTILE, (int)((long)E - e0));

    const short8* Bp  = reinterpret_cast<const short8*>(wsb);
    const short8* W1p = reinterpret_cast<const short8*>(wsb + FD * FD);

    // ---------------- fc1: W = silu(attr @ W1 + b1), A-frag direct from global ----
    // Post-silu values kept in Wr0/Wr1 (epilogue layout) AND written to sW
    // (features layout, stride 36 = conflict-free).
    float Wr0[4], Wr1[4];
    {
        int rowA = (int)e0 + ((l15 < nv) ? l15 : 0);
        const float* ar = xe_attr + (size_t)rowA * ATTRD + quad * 8;
        union { short8 v; unsigned short u[8]; } AF0;
        #pragma unroll
        for (int j = 0; j < 8; ++j) AF0.u[j] = bf16rne(ar[j]);

        f32x4 c0 = (f32x4){0.f, 0.f, 0.f, 0.f};
        f32x4 c1 = (f32x4){0.f, 0.f, 0.f, 0.f};
        c0 = __builtin_amdgcn_mfma_f32_16x16x32_bf16(AF0.v, W1p[lane],      c0, 0, 0, 0);
        c1 = __builtin_amdgcn_mfma_f32_16x16x32_bf16(AF0.v, W1p[64 + lane], c1, 0, 0, 0);

        // rank-1 correction for attr col 32, + bias, + silu
        float b1a  = b1[l15],            b1b  = b1[16 + l15];
        float w32a = W1[32 * D + l15],   w32b = W1[32 * D + 16 + l15];
        #pragma unroll
        for (int r = 0; r < 4; ++r) {
            int e = quad * 4 + r;
            int rowC = (int)e0 + ((e < nv) ? e : 0);
            float a32 = xe_attr[(size_t)rowC * ATTRD + 32];
            float x0 = c0[r] + b1a + a32 * w32a;
            float x1 = c1[r] + b1b + a32 * w32b;
            float s0 = x0 * __builtin_amdgcn_rcpf(1.0f + __expf(-x0));
            float s1 = x1 * __builtin_amdgcn_rcpf(1.0f + __expf(-x1));
            Wr0[r] = s0;
            Wr1[r] = s1;
            sW[e * SWSTR + l15]      = s0;
            sW[e * SWSTR + 16 + l15] = s1;
        }
    }

    // ---------------- features: lane owns edge l15, cols quad*8..+8 ----------------
    // tanh(feature) values go straight to sA in mm1/mm2 A-layout (row l15,
    // feature f occupies cols f*32..f*32+32 of the 160-wide row). This frees
    // the AF[5] register block that previously capped occupancy at 4 waves/SIMD.
    // Program order guarantees the sW reads below complete before the sA
    // writes clobber the aliased region.
    {
        int ei = (int)e0 + ((l15 < nv) ? l15 : 0);
        int se = esrc[ei], de = edst[ei];
        const float4* xsr = reinterpret_cast<const float4*>(xn + (size_t)se * D + quad * 8);
        const float4* xdr = reinterpret_cast<const float4*>(xn + (size_t)de * D + quad * 8);
        float4 xs0 = xsr[0], xs1 = xsr[1];
        float4 xd0 = xdr[0], xd1 = xdr[1];
        float4 wv0 = *reinterpret_cast<const float4*>(&sW[l15 * SWSTR + quad * 8]);
        float4 wv1 = *reinterpret_cast<const float4*>(&sW[l15 * SWSTR + quad * 8 + 4]);
        float xs[8] = {xs0.x, xs0.y, xs0.z, xs0.w, xs1.x, xs1.y, xs1.z, xs1.w};
        float xd[8] = {xd0.x, xd0.y, xd0.z, xd0.w, xd1.x, xd1.y, xd1.z, xd1.w};
        float wf[8] = {wv0.x, wv0.y, wv0.z, wv0.w, wv1.x, wv1.y, wv1.z, wv1.w};
        union { short8 v; unsigned short u[8]; } T[5];
        #pragma unroll
        for (int c = 0; c < 8; ++c) {
            float g = wf[c] * (xs[c] - xd[c]);
            float a = wf[c] * (xs[c] + xd[c]) * 0.5f;
            T[0].u[c] = bf16rne(fast_tanh(g));
            T[1].u[c] = bf16rne(fast_tanh(a));
            T[2].u[c] = bf16rne(fast_tanh(g * a));
            T[3].u[c] = bf16rne(fast_tanh(g * g));
            T[4].u[c] = bf16rne(fast_tanh(a * a));
        }
        #pragma unroll
        for (int f = 0; f < 5; ++f)
            *reinterpret_cast<short8*>(&sA[l15 * ASTR + f * 32 + quad * 8]) = T[f].v;
    }

    // ---------------- matmul 1: C[nt] (16 edges x 160 cols per wave) ----------------
    // A-frag per K-step from LDS (amortized over 10 MFMAs), same address family
    // as mm2 -> conflict behavior unchanged.
    f32x4 C[10];
    #pragma unroll
    for (int t = 0; t < 10; ++t) C[t] = (f32x4){0.f, 0.f, 0.f, 0.f};
    #pragma unroll
    for (int ks = 0; ks < NKS; ++ks) {
        short8 af1 = *reinterpret_cast<const short8*>(&sA[l15 * ASTR + ks * 32 + quad * 8]);
        #pragma unroll
        for (int nt = 0; nt < 10; ++nt)
            C[nt] = __builtin_amdgcn_mfma_f32_16x16x32_bf16(
                af1, Bp[(nt * NKS + ks) * 64 + lane], C[nt], 0, 0, 0);
    }

    // ---------------- tv_norm: full row in 16-lane group, shfl-only ----------------
    float mean[4], scale[4];
    #pragma unroll
    for (int r = 0; r < 4; ++r) {
        float s = 0.f, q = 0.f;
        #pragma unroll
        for (int t = 0; t < 10; ++t) { float v = C[t][r]; s += v; q += v * v; }
        #pragma unroll
        for (int m = 1; m < 16; m <<= 1) { s += __shfl_xor(s, m); q += __shfl_xor(q, m); }
        mean[r] = s * (1.0f / FD);
        scale[r] = __builtin_amdgcn_rsqf(q - (float)FD * mean[r] * mean[r] + 1e-3f);
    }

    // ---------------- tanh(tv_norm) -> wave-local LDS (transpose for mm2 A) --------
    // Overwrites sA (features fully consumed by mm1; program order protects).
    #pragma unroll
    for (int t = 0; t < 10; ++t)
        #pragma unroll
        for (int r = 0; r < 4; ++r) {
            float v = fast_tanh((C[t][r] - mean[r]) * scale[r]);
            sA[(quad * 4 + r) * ASTR + t * 16 + l15] = bf16rne(v);
        }

    // ---------------- matmul 2 (A from wave-local LDS, same-wave ordering) ---------
    #pragma unroll
    for (int t = 0; t < 10; ++t) C[t] = (f32x4){0.f, 0.f, 0.f, 0.f};
    #pragma unroll
    for (int ks = 0; ks < NKS; ++ks) {
        short8 af2 = *reinterpret_cast<const short8*>(&sA[l15 * ASTR + ks * 32 + quad * 8]);
        #pragma unroll
        for (int nt = 0; nt < 10; ++nt)
            C[nt] = __builtin_amdgcn_mfma_f32_16x16x32_bf16(
                af2, Bp[(nt * NKS + ks) * 64 + lane], C[nt], 0, 0, 0);
    }

    // ---------------- epilogue: msg = tile(W,5)*tanh; chunk-reduce; atomics --------
    // W comes from registers (fc1 output layout == epilogue layout), no LDS read.
    #pragma unroll
    for (int r = 0; r < 4; ++r) {
        int e = quad * 4 + r;
        if (e >= nv) continue;
        int sd = edst[e0 + e], ss = esrc[e0 + e];
        #pragma unroll
        for (int par = 0; par < 2; ++par) {
            int c = par * 16 + l15;
            float wv = (par == 0) ? Wr0[r] : Wr1[r];
            float m0 = fast_tanh(C[par][r]) * wv;
            float A4 = (fast_tanh(C[par + 2][r]) + fast_tanh(C[par + 4][r])
                      + fast_tanh(C[par + 6][r]) + fast_tanh(C[par + 8][r])) * wv;
            atomicAdd(out + (size_t)sd * D + c, m0 + 0.5f * A4);
            atomicAdd(out + (size_t)ss * D + c, 0.5f * A4 - m0);
        }
    }
}

extern "C" void kernel_launch(void* const* d_in, const int* in_sizes, int n_in,
                              void* d_out, int out_size, void* d_ws, size_t ws_size,
                              hipStream_t stream)
{
    const float* xn   = (const float*)d_in[0];
    const float* attr = (const float*)d_in[1];
    const float* W1   = (const float*)d_in[2];
    const float* b1   = (const float*)d_in[3];
    const float* Wd1  = (const float*)d_in[4];
    const int*   esrc = (const int*)d_in[5];
    const int*   edst = (const int*)d_in[6];
    float* out = (float*)d_out;
    unsigned short* wsb = (unsigned short*)d_ws;   // 26624 bf16 packed B-frags

    const int E = in_sizes[5];

    hipMemsetAsync(d_out, 0, (size_t)out_size * sizeof(float), stream);
    prep_weights<<<(FD * FD + 32 * D + 255) / 256, 256, 0, stream>>>(Wd1, W1, wsb);
    const long tiles = ((long)E + WTILE - 1) / WTILE;
    const int grid = (int)((tiles + 3) / 4);
    prop_mfma<<<grid, BLOCK, 0, stream>>>(xn, attr, W1, b1, wsb, esrc, edst, out, E);
}

// Round 3
// 774.349 us; speedup vs baseline: 2.0893x; 1.1857x over previous
//
#include <hip/hip_runtime.h>
#include <cstdint>

// N=100000 nodes, E=1.6M edges, D=32, 5D=160, ATTR=33
constexpr int D      = 32;
constexpr int FD     = 160;
constexpr int ATTRD  = 33;
constexpr int WTILE  = 32;    // edges per wave: 32x32x16 MFMA halves B-reads/edge vs 16x16
constexpr int BLOCK  = 256;   // 4 waves/block, wave w -> tile blockIdx*4+w
constexpr int NKS    = 10;    // K-steps of 16 for the 160-K GEMMs
constexpr int NNT    = 5;     // N-tiles of 32
constexpr int ASTR   = 168;   // sA row stride (shorts): 336 B; dword-stride 84 ≡ 20 mod 32
                              // -> b128 reads land 8 lanes per 4-bank group = bank-balanced
constexpr int SWSTR  = 36;    // sW row stride (floats): 144 B rows, 16B-aligned float4
constexpr int WBYTES = 10752; // per-wave shared = max(32*168*2=10752 sA, 32*36*4=4608 sW)
                              // LDS/block 43008 -> 3 blocks/CU; matches (256,3) reg budget

typedef __attribute__((ext_vector_type(8)))  short short8;  // 8 bf16 (4 VGPRs) MFMA A/B frag
typedef __attribute__((ext_vector_type(16))) float f32x16;  // 32x32 MFMA C/D frag

__device__ __forceinline__ float fast_tanh(float x) {
    float e = __expf(2.0f * x);
    return 1.0f - 2.0f * __builtin_amdgcn_rcpf(e + 1.0f);
}
// RNE bf16, no NaN handling (inputs finite by construction)
__device__ __forceinline__ unsigned short bf16rne(float x) {
    union { float f; unsigned u; } v; v.f = x;
    unsigned r = v.u + 0x7fffu + ((v.u >> 16) & 1u);
    return (unsigned short)(r >> 16);
}
__device__ __forceinline__ f32x16 zero16() {
    return (f32x16){0.f,0.f,0.f,0.f,0.f,0.f,0.f,0.f,0.f,0.f,0.f,0.f,0.f,0.f,0.f,0.f};
}

// Pack Wd1 (160x160) and W1 rows 0..31 (32x32) into bf16 B-fragment lane order
// for mfma_f32_32x32x16_bf16. B-chunk (nt,ks): lane L holds
// B[ks*16 + (L>>5)*8 + j][nt*32 + (L&31)], j<8 (contiguous-8 k per half, same
// doubling pattern as the verified 16x16x32 layout).
// ws layout (shorts): [0, 25600) Wd1 frags; [25600, 26624) W1 frags (2 K-steps).
// W1 row 32 is applied as a rank-1 VALU correction in the kernel.
__global__ void prep_weights(const float* __restrict__ Wd1,
                             const float* __restrict__ W1,
                             unsigned short* __restrict__ wsb) {
    int t = blockIdx.x * blockDim.x + threadIdx.x;
    if (t < FD * FD) {
        int k = t / FD, n = t - k * FD;
        int ks = k >> 4, half = (k >> 3) & 1, j = k & 7;
        int nt = n >> 5, col = n & 31;
        int dst = ((nt * NKS + ks) * 64 + half * 32 + col) * 8 + j;
        wsb[dst] = bf16rne(Wd1[t]);
    } else if (t < FD * FD + 32 * D) {
        int t2 = t - FD * FD;            // t2 = k*32 + n, k in [0,32)
        int k = t2 >> 5, n = t2 & 31;
        int ks = k >> 4, half = (k >> 3) & 1, j = k & 7;
        int dst = FD * FD + (ks * 64 + half * 32 + n) * 8 + j;
        wsb[dst] = bf16rne(W1[k * D + n]);
    }
}

// Theory (R3): kernel was L2-BW-bound on the B-frag stream (100 KB/wave per 16
// edges = 10.2 GB L2 ~ 300 us). 32x32x16 MFMA with 32 edges/wave halves B-bytes
// per edge. (256,3): cap 170, live ~140 (C 80 + Wc 16 + transients) -> no spill.
// No __syncthreads: each wave owns 32 edges end-to-end; LDS per-wave; same-wave
// DS ordering is program order. Alias timeline: fc1 writes sW -> features read
// sW fully (wf preloaded BEFORE any sA write!) -> features write sA -> mm1
// reads sA -> tvnorm overwrites sA -> mm2 reads sA -> epilogue registers only.
__global__ __launch_bounds__(BLOCK, 3)
void prop_mfma(const float* __restrict__ xn,
               const float* __restrict__ xe_attr,
               const float* __restrict__ W1,
               const float* __restrict__ b1,
               const unsigned short* __restrict__ wsb,
               const int*   __restrict__ esrc,
               const int*   __restrict__ edst,
               float* __restrict__ out,
               int E)
{
    __shared__ __align__(16) unsigned char sMem[4 * WBYTES];   // 43008 B/block

    const int tid  = threadIdx.x;
    const int lane = tid & 63;
    const int w    = tid >> 6;
    const int col  = lane & 31;   // output column / edge index role
    const int half = lane >> 5;   // k-half selector
    unsigned char* wbase = sMem + w * WBYTES;
    float*          sW = reinterpret_cast<float*>(wbase);          // [32][SWSTR] f32
    unsigned short* sA = reinterpret_cast<unsigned short*>(wbase); // [32][ASTR] bf16

    const long tile = (long)blockIdx.x * 4 + w;
    const long e0   = tile * WTILE;
    if (e0 >= (long)E) return;                      // wave-uniform
    const int nv = min(WTILE, (int)((long)E - e0));

    const short8* Bp  = reinterpret_cast<const short8*>(wsb);
    const short8* W1p = reinterpret_cast<const short8*>(wsb + FD * FD);

    // ---------------- fc1: W = silu(attr @ W1 + b1), M=32 ------------------------
    // C/D layout: lane holds col=lane&31, rows (r&3)+8*(r>>2)+4*half -- kept in
    // Wc (epilogue layout) AND written to sW[row][col] for the features stage.
    f32x16 Wc;
    {
        int rowA = (int)e0 + ((col < nv) ? col : 0);
        const float* ar = xe_attr + (size_t)rowA * ATTRD;
        union { short8 v; unsigned short u[8]; } A0, A1;
        #pragma unroll
        for (int j = 0; j < 8; ++j) {
            A0.u[j] = bf16rne(ar[half * 8 + j]);         // k = 0..15
            A1.u[j] = bf16rne(ar[16 + half * 8 + j]);    // k = 16..31
        }
        f32x16 c = zero16();
        c = __builtin_amdgcn_mfma_f32_32x32x16_bf16(A0.v, W1p[lane],      c, 0, 0, 0);
        c = __builtin_amdgcn_mfma_f32_32x32x16_bf16(A1.v, W1p[64 + lane], c, 0, 0, 0);

        float b1c  = b1[col];
        float w32c = W1[32 * D + col];
        #pragma unroll
        for (int r = 0; r < 16; ++r) {
            int row  = (r & 3) + 8 * (r >> 2) + 4 * half;
            int rowC = (int)e0 + ((row < nv) ? row : 0);
            float a32 = xe_attr[(size_t)rowC * ATTRD + 32];
            float x = c[r] + b1c + a32 * w32c;
            float s = x * __builtin_amdgcn_rcpf(1.0f + __expf(-x));
            Wc[r] = s;
            sW[row * SWSTR + col] = s;   // bank (4*row+col)%32: 2 lanes/bank, free
        }
    }

    // ---------------- features: lane owns edge col, 16 channels ------------------
    // Channels: {half*8..+8} u {16+half*8..+8}; the two halves of the wave cover
    // all 32 channels of each edge. Written to sA in mm1/mm2 A-frag layout.
    // wf is fully preloaded BEFORE any sA write (sA aliases sW!).
    {
        int e  = (col < nv) ? col : 0;
        int ei = (int)e0 + e;
        int se = esrc[ei], de = edst[ei];
        const float* xsp = xn + (size_t)se * D;
        const float* xdp = xn + (size_t)de * D;
        float4 wfa = *reinterpret_cast<const float4*>(&sW[e * SWSTR + half * 8]);
        float4 wfb = *reinterpret_cast<const float4*>(&sW[e * SWSTR + half * 8 + 4]);
        float4 wfc = *reinterpret_cast<const float4*>(&sW[e * SWSTR + 16 + half * 8]);
        float4 wfd = *reinterpret_cast<const float4*>(&sW[e * SWSTR + 16 + half * 8 + 4]);
        float wf16[16] = {wfa.x,wfa.y,wfa.z,wfa.w, wfb.x,wfb.y,wfb.z,wfb.w,
                          wfc.x,wfc.y,wfc.z,wfc.w, wfd.x,wfd.y,wfd.z,wfd.w};
        #pragma unroll
        for (int p = 0; p < 2; ++p) {
            int cb = p * 16 + half * 8;               // channel base
            float4 xsa = *reinterpret_cast<const float4*>(xsp + cb);
            float4 xsb = *reinterpret_cast<const float4*>(xsp + cb + 4);
            float4 xda = *reinterpret_cast<const float4*>(xdp + cb);
            float4 xdb = *reinterpret_cast<const float4*>(xdp + cb + 4);
            float xs8[8] = {xsa.x,xsa.y,xsa.z,xsa.w, xsb.x,xsb.y,xsb.z,xsb.w};
            float xd8[8] = {xda.x,xda.y,xda.z,xda.w, xdb.x,xdb.y,xdb.z,xdb.w};
            union { short8 v; unsigned short u[8]; } T[5];
            #pragma unroll
            for (int c = 0; c < 8; ++c) {
                float wfv = wf16[p * 8 + c];
                float g = wfv * (xs8[c] - xd8[c]);
                float a = wfv * (xs8[c] + xd8[c]) * 0.5f;
                T[0].u[c] = bf16rne(fast_tanh(g));
                T[1].u[c] = bf16rne(fast_tanh(a));
                T[2].u[c] = bf16rne(fast_tanh(g * a));
                T[3].u[c] = bf16rne(fast_tanh(g * g));
                T[4].u[c] = bf16rne(fast_tanh(a * a));
            }
            #pragma unroll
            for (int f = 0; f < 5; ++f)
                *reinterpret_cast<short8*>(&sA[e * ASTR + f * 32 + cb]) = T[f].v;
        }
    }

    // ---------------- matmul 1: 32 edges x 160 cols ------------------------------
    // A-frag: lane reads A[row=col][k=ks*16+half*8..+8] -- one b128 per K-step,
    // amortized over 5 MFMAs. B streams from L2 (51.2 KB per matmul per wave).
    f32x16 C[NNT];
    #pragma unroll
    for (int t = 0; t < NNT; ++t) C[t] = zero16();
    #pragma unroll
    for (int ks = 0; ks < NKS; ++ks) {
        short8 af = *reinterpret_cast<const short8*>(&sA[col * ASTR + ks * 16 + half * 8]);
        #pragma unroll
        for (int nt = 0; nt < NNT; ++nt)
            C[nt] = __builtin_amdgcn_mfma_f32_32x32x16_bf16(
                af, Bp[(nt * NKS + ks) * 64 + lane], C[nt], 0, 0, 0);
    }

    // ---------------- tv_norm + tanh -> sA (transpose for mm2 A) -----------------
    // Row sums: 32-lane butterfly within each half-group (lanes of a half hold
    // the same 16 rows, all 32 cols). mean/scale are transient (no reg array).
    #pragma unroll
    for (int r = 0; r < 16; ++r) {
        float s = 0.f, q = 0.f;
        #pragma unroll
        for (int nt = 0; nt < NNT; ++nt) { float v = C[nt][r]; s += v; q += v * v; }
        #pragma unroll
        for (int m = 1; m < 32; m <<= 1) { s += __shfl_xor(s, m); q += __shfl_xor(q, m); }
        float mean = s * (1.0f / FD);
        float sc = __builtin_amdgcn_rsqf(q - (float)FD * mean * mean + 1e-3f);
        int row = (r & 3) + 8 * (r >> 2) + 4 * half;
        #pragma unroll
        for (int nt = 0; nt < NNT; ++nt) {
            float v = fast_tanh((C[nt][r] - mean) * sc);
            sA[row * ASTR + nt * 32 + col] = bf16rne(v);
        }
    }

    // ---------------- matmul 2 (A from wave-local LDS) ---------------------------
    #pragma unroll
    for (int t = 0; t < NNT; ++t) C[t] = zero16();
    #pragma unroll
    for (int ks = 0; ks < NKS; ++ks) {
        short8 af = *reinterpret_cast<const short8*>(&sA[col * ASTR + ks * 16 + half * 8]);
        #pragma unroll
        for (int nt = 0; nt < NNT; ++nt)
            C[nt] = __builtin_amdgcn_mfma_f32_32x32x16_bf16(
                af, Bp[(nt * NKS + ks) * 64 + lane], C[nt], 0, 0, 0);
    }

    // ---------------- epilogue: msg = tile(W,5)*tanh; atomics --------------------
    // C[nt] tile nt == feature block nt; col within tile == output channel.
    // W from Wc registers (fc1 layout == epilogue layout), no LDS read.
    #pragma unroll
    for (int r = 0; r < 16; ++r) {
        int row = (r & 3) + 8 * (r >> 2) + 4 * half;
        if (row >= nv) continue;
        int sd = edst[e0 + row], ss = esrc[e0 + row];
        float wv = Wc[r];
        float m0 = fast_tanh(C[0][r]) * wv;
        float A4 = (fast_tanh(C[1][r]) + fast_tanh(C[2][r])
                  + fast_tanh(C[3][r]) + fast_tanh(C[4][r])) * wv;
        atomicAdd(out + (size_t)sd * D + col, m0 + 0.5f * A4);
        atomicAdd(out + (size_t)ss * D + col, 0.5f * A4 - m0);
    }
}

extern "C" void kernel_launch(void* const* d_in, const int* in_sizes, int n_in,
                              void* d_out, int out_size, void* d_ws, size_t ws_size,
                              hipStream_t stream)
{
    const float* xn   = (const float*)d_in[0];
    const float* attr = (const float*)d_in[1];
    const float* W1   = (const float*)d_in[2];
    const float* b1   = (const float*)d_in[3];
    const float* Wd1  = (const float*)d_in[4];
    const int*   esrc = (const int*)d_in[5];
    const int*   edst = (const int*)d_in[6];
    float* out = (float*)d_out;
    unsigned short* wsb = (unsigned short*)d_ws;   // 26624 bf16 packed B-frags

    const int E = in_sizes[5];

    hipMemsetAsync(d_out, 0, (size_t)out_size * sizeof(float), stream);
    prep_weights<<<(FD * FD + 32 * D + 255) / 256, 256, 0, stream>>>(Wd1, W1, wsb);
    const long tiles = ((long)E + WTILE - 1) / WTILE;
    const int grid = (int)((tiles + 3) / 4);
    prop_mfma<<<grid, BLOCK, 0, stream>>>(xn, attr, W1, b1, wsb, esrc, edst, out, E);
}